// Round 5
// baseline (180.082 us; speedup 1.0000x reference)
//
#include <hip/hip_runtime.h>

#define BATCH 4096
#define DIM 4096
#define NSPLIT 64
#define ROWS_PB 128
#define NCHUNK 32            // BATCH / ROWS_PB (y-tile granularity, K2 grid)
#define CPB 4                // chunks per K1 block
#define BLKX 8               // NCHUNK / CPB
#define BN_EPS 1e-3f

typedef __attribute__((ext_vector_type(8))) short bf16x8;
typedef __attribute__((ext_vector_type(8))) unsigned short ushort8;
typedef __attribute__((ext_vector_type(4))) float f32x4;

__device__ inline unsigned short f2bf(float f) {
    union { float f; unsigned int u; } c; c.f = f;
    unsigned int u = c.u;
    u += 0x7FFFu + ((u >> 16) & 1u);   // round-to-nearest-even
    return (unsigned short)(u >> 16);
}

__device__ inline float bf2f(unsigned short h) {
    union { unsigned int u; float f; } c;
    c.u = (unsigned int)h << 16;
    return c.f;
}

// K1: GEMM once, 4 row-chunks per block, software-pipelined.
//  - x fragments global->reg, double-buffered: chunk c+1's 8 independent
//    16B loads are in flight while chunk c converts + MFMAs.
//  - W block staged via LDS once per block (amortized over 4 chunks).
//  - y stored bf16 into each chunk's own out-tile (identical layout to the
//    round-4 kernel, so K2's load path is unchanged).
//  - part: ONE pre-summed partial per block -> 8 per split (256 KB ws).
//  - Bias dropped: cancels exactly under BatchNorm mean subtraction.
__global__ __launch_bounds__(256) void gemm_stats(
    const float* __restrict__ x, const float* __restrict__ w,
    float* __restrict__ part, float* __restrict__ out)
{
    __shared__ unsigned short wt[64][72];
    __shared__ float red1[4][64], red2[4][64];

    const int s  = blockIdx.y;
    const int c0 = blockIdx.x * CPB;      // first chunk index
    const int t  = threadIdx.x;
    const int lane = t & 63, wave = t >> 6;
    const int quad = lane >> 4, l16 = lane & 15;

    // stage W_s transposed (fp32 -> bf16), coalesced float4 reads
    for (int i = t; i < 1024; i += 256) {
        int k = i >> 4, c4 = i & 15;
        float4 v = *(const float4*)(w + (size_t)(s*64 + k) * DIM + s*64 + c4*4);
        wt[c4*4 + 0][k] = f2bf(v.x);
        wt[c4*4 + 1][k] = f2bf(v.y);
        wt[c4*4 + 2][k] = f2bf(v.z);
        wt[c4*4 + 3][k] = f2bf(v.w);
    }

    auto load_chunk = [&](float4 (&dst)[2][2][2], int c) {
        const int rr0 = (c0 + c) * ROWS_PB;
        #pragma unroll
        for (int rt = 0; rt < 2; rt++)
            #pragma unroll
            for (int kk = 0; kk < 2; kk++)
                #pragma unroll
                for (int h = 0; h < 2; h++)
                    dst[rt][kk][h] = *(const float4*)(
                        x + (size_t)(rr0 + wave*32 + rt*16 + l16) * DIM
                          + s*64 + kk*32 + quad*8 + h*4);
    };

    float4 xvA[2][2][2], xvB[2][2][2];
    load_chunk(xvA, 0);

    __syncthreads();   // wt ready

    bf16x8 bfr[4][2];
    #pragma unroll
    for (int ct = 0; ct < 4; ct++)
        #pragma unroll
        for (int kk = 0; kk < 2; kk++)
            bfr[ct][kk] = *(const bf16x8*)&wt[ct*16 + l16][kk*32 + quad*8];

    float s1[4], s2[4];
    #pragma unroll
    for (int ct = 0; ct < 4; ct++) { s1[ct] = 0.f; s2[ct] = 0.f; }

    #pragma unroll
    for (int c = 0; c < CPB; c++) {
        float4 (&cur)[2][2][2] = (c & 1) ? xvB : xvA;   // compile-time after unroll
        float4 (&nxt)[2][2][2] = (c & 1) ? xvA : xvB;
        if (c < CPB - 1) load_chunk(nxt, c + 1);        // overlap with compute below

        bf16x8 af[2][2];
        #pragma unroll
        for (int rt = 0; rt < 2; rt++)
            #pragma unroll
            for (int kk = 0; kk < 2; kk++) {
                bf16x8 a;
                a[0] = (short)f2bf(cur[rt][kk][0].x);
                a[1] = (short)f2bf(cur[rt][kk][0].y);
                a[2] = (short)f2bf(cur[rt][kk][0].z);
                a[3] = (short)f2bf(cur[rt][kk][0].w);
                a[4] = (short)f2bf(cur[rt][kk][1].x);
                a[5] = (short)f2bf(cur[rt][kk][1].y);
                a[6] = (short)f2bf(cur[rt][kk][1].z);
                a[7] = (short)f2bf(cur[rt][kk][1].w);
                af[rt][kk] = a;
            }

        f32x4 acc[2][4];
        #pragma unroll
        for (int rt = 0; rt < 2; rt++)
            #pragma unroll
            for (int ct = 0; ct < 4; ct++)
                acc[rt][ct] = (f32x4){0.f, 0.f, 0.f, 0.f};

        #pragma unroll
        for (int kk = 0; kk < 2; kk++)
            #pragma unroll
            for (int rt = 0; rt < 2; rt++)
                #pragma unroll
                for (int ct = 0; ct < 4; ct++)
                    acc[rt][ct] = __builtin_amdgcn_mfma_f32_16x16x32_bf16(
                        af[rt][kk], bfr[ct][kk], acc[rt][ct], 0, 0, 0);

        // pack y -> bf16 into this chunk's own out-tile scratch
        const int rr0 = (c0 + c) * ROWS_PB;
        #pragma unroll
        for (int j = 0; j < 4; j++) {
            const int f0 = 2*j, f1 = 2*j + 1;
            const f32x4 a0 = acc[f0 >> 2][f0 & 3];
            const f32x4 a1 = acc[f1 >> 2][f1 & 3];
            ushort8 pk;
            pk[0] = f2bf(a0[0]); pk[1] = f2bf(a0[1]);
            pk[2] = f2bf(a0[2]); pk[3] = f2bf(a0[3]);
            pk[4] = f2bf(a1[0]); pk[5] = f2bf(a1[1]);
            pk[6] = f2bf(a1[2]); pk[7] = f2bf(a1[3]);
            int u = j*256 + t;   // 1024 ushort8 units = 64 rows x 16 units
            unsigned short* dst =
                (unsigned short*)(out + (size_t)(rr0 + (u >> 4)) * DIM + s*64)
                + (u & 15) * 8;
            *(ushort8*)dst = pk;
        }

        // column partial accumulation (across all 4 chunks)
        #pragma unroll
        for (int rt = 0; rt < 2; rt++)
            #pragma unroll
            for (int ct = 0; ct < 4; ct++)
                #pragma unroll
                for (int r = 0; r < 4; r++) {
                    float v = acc[rt][ct][r];
                    s1[ct] += v; s2[ct] += v * v;
                }
    }

    // wave shuffle -> cross-wave LDS -> one pre-summed partial per block
    #pragma unroll
    for (int ct = 0; ct < 4; ct++) {
        float a = s1[ct], b = s2[ct];
        a += __shfl_xor(a, 16); b += __shfl_xor(b, 16);
        a += __shfl_xor(a, 32); b += __shfl_xor(b, 32);
        if (quad == 0) {
            red1[wave][ct*16 + l16] = a;
            red2[wave][ct*16 + l16] = b;
        }
    }
    __syncthreads();
    if (t < 64) {
        float a = red1[0][t] + red1[1][t] + red1[2][t] + red1[3][t];
        float b = red2[0][t] + red2[1][t] + red2[2][t] + red2[3][t];
        size_t base = (size_t)(s * BLKX + blockIdx.x) * 128;
        part[base + t]      = a;
        part[base + 64 + t] = b;
    }
}

// K2: finalize stats (parallel reduce, 8 partials/split), read back the
// block's own bf16 y tile, BN + ReLU, fp32 scatter store. Explicit
// vmcnt(0)+barrier orders tile-read before any tile-overwrite.
__global__ __launch_bounds__(256) void bn_apply(
    const float* __restrict__ part, const float* __restrict__ gamma,
    const float* __restrict__ beta, float* __restrict__ out)
{
    __shared__ float redA[4][64], redB[4][64];
    __shared__ float scol[64], shcol[64];

    const int s  = blockIdx.y;
    const int r0 = blockIdx.x * ROWS_PB;
    const int t  = threadIdx.x;
    const int lane = t & 63, wave = t >> 6;
    const int quad = lane >> 4, l16 = lane & 15;

    // load own y tile early (issue all 4 loads before the reduce)
    ushort8 yv[4];
    #pragma unroll
    for (int j = 0; j < 4; j++) {
        int u = j*256 + t;
        const unsigned short* src =
            (const unsigned short*)(out + (size_t)(r0 + (u >> 4)) * DIM + s*64)
            + (u & 15) * 8;
        yv[j] = *(const ushort8*)src;
    }

    // parallel part-reduce: wave g covers partials g*2, g*2+1; col = lane
    {
        float a = 0.f, b = 0.f;
        #pragma unroll
        for (int p2 = 0; p2 < 2; p2++) {
            int p = wave*2 + p2;
            size_t base = (size_t)(s * BLKX + p) * 128;
            a += part[base + lane];
            b += part[base + 64 + lane];
        }
        redA[wave][lane] = a;
        redB[wave][lane] = b;
    }

    // all global loads (y + part) must have landed before any thread stores
    asm volatile("s_waitcnt vmcnt(0)" ::: "memory");
    __syncthreads();

    if (t < 64) {
        float a = redA[0][t] + redA[1][t] + redA[2][t] + redA[3][t];
        float b = redB[0][t] + redB[1][t] + redB[2][t] + redB[3][t];
        float mean = a * (1.f / BATCH);
        float var  = b * (1.f / BATCH) - mean * mean;
        float rstd = rsqrtf(var + BN_EPS);
        float sc = gamma[s*64 + t] * rstd;
        scol[t]  = sc;
        shcol[t] = beta[s*64 + t] - mean * sc;
    }
    __syncthreads();

    #pragma unroll
    for (int j = 0; j < 4; j++) {
        #pragma unroll
        for (int h = 0; h < 2; h++) {
            const int f  = 2*j + h;
            const int rt = f >> 2, ct = f & 3;
            const int col = ct*16 + l16;
            const float sc = scol[col], sh = shcol[col];
            #pragma unroll
            for (int r = 0; r < 4; r++) {
                float v = fmaxf(fmaf(bf2f((unsigned short)yv[j][h*4 + r]), sc, sh), 0.f);
                int row = r0 + wave*32 + rt*16 + quad*4 + r;
                out[(size_t)row * DIM + s*64 + col] = v;
            }
        }
    }
}

extern "C" void kernel_launch(void* const* d_in, const int* in_sizes, int n_in,
                              void* d_out, int out_size, void* d_ws, size_t ws_size,
                              hipStream_t stream) {
    const float* x     = (const float*)d_in[0];
    const float* w     = (const float*)d_in[1];
    // d_in[2] = bias: cancels exactly in BatchNorm (mean subtraction) — unused
    const float* gamma = (const float*)d_in[3];
    const float* beta  = (const float*)d_in[4];
    float* out  = (float*)d_out;
    float* part = (float*)d_ws;    // 256 KB used — inside the validated 1 MiB

    gemm_stats<<<dim3(BLKX, NSPLIT), 256, 0, stream>>>(x, w, part, out);
    bn_apply<<<dim3(NCHUNK, NSPLIT), 256, 0, stream>>>(part, gamma, beta, out);
}